// Round 6
// baseline (309.425 us; speedup 1.0000x reference)
//
#include <hip/hip_runtime.h>
#include <hip/hip_bf16.h>
#include <math.h>

namespace {
constexpr int EDIM  = 512;
constexpr int DDIM  = 1024;
constexpr int ADIM  = 128;
constexpr int FDIM  = 32;
constexpr int KW    = 31;
constexpr int BATCH = 128;
constexpr int TDIM  = 512;

constexpr int ASTR = 520;    // persistent A stride in ushorts (1040 B; 260 dw % 32 = 4 -> 2-way, free)
constexpr int BSTR = 40;     // B stride in ushorts (80 B; proven R1 layout, 2-way, free)

typedef __attribute__((ext_vector_type(8))) short short8;
typedef __attribute__((ext_vector_type(4))) float floatx4;

__device__ __forceinline__ float fast_tanh(float x) {
  x = fminf(9.0f, fmaxf(-9.0f, x));
  float e = __expf(2.0f * x);
  return (e - 1.0f) / (e + 1.0f);
}

__device__ __forceinline__ ushort2 pack_bf16(float x, float y) {
  union { __hip_bfloat162 h; ushort2 u; } cv;
  cv.h = __float22bfloat162_rn(make_float2(x, y));
  return cv.u;
}

__device__ __forceinline__ short8 pack8(floatx4 a, floatx4 b) {
  union { ushort2 u[4]; short8 v; } o;
  o.u[0] = pack_bf16(a[0], a[1]); o.u[1] = pack_bf16(a[2], a[3]);
  o.u[2] = pack_bf16(b[0], b[1]); o.u[3] = pack_bf16(b[2], b[3]);
  return o.v;
}

__device__ __forceinline__ int ld_acq(int* p) {
  return __hip_atomic_load(p, __ATOMIC_ACQUIRE, __HIP_MEMORY_SCOPE_WORKGROUP);
}
__device__ __forceinline__ void add_rel(int* p) {
  __hip_atomic_fetch_add(p, 1, __ATOMIC_RELEASE, __HIP_MEMORY_SCOPE_WORKGROUP);
}

__device__ __forceinline__ float bf16_lo(unsigned v) {
  union { unsigned u; float f; } c; c.u = v << 16; return c.f;
}
__device__ __forceinline__ float bf16_hi(unsigned v) {
  union { unsigned u; float f; } c; c.u = v & 0xffff0000u; return c.f;
}

// dec_p[b,a] = sum_d dec[b,d] * Wdec[a,d]   grid (B, 4), 256 thr  (fallback)
__global__ __launch_bounds__(256)
void dec_proj_kernel(const float* __restrict__ dec,
                     const float* __restrict__ Wdec,
                     float* __restrict__ dec_p) {
  int b = blockIdx.x, az = blockIdx.y;
  int tid = threadIdx.x;
  int al = tid >> 3, seg = tid & 7;
  int a = az * 32 + al;
  const float* dv = dec + (size_t)b * DDIM;
  const float* wv = Wdec + (size_t)a * DDIM;
  float s = 0.f;
  #pragma unroll 8
  for (int it = 0; it < 32; ++it) {
    int d = it * 32 + seg * 4;
    float4 d4 = *(const float4*)(dv + d);
    float4 w4 = *(const float4*)(wv + d);
    s += d4.x * w4.x + d4.y * w4.y + d4.z * w4.z + d4.w * w4.w;
  }
  s += __shfl_xor(s, 1, 64);
  s += __shfl_xor(s, 2, 64);
  s += __shfl_xor(s, 4, 64);
  if (seg == 0) dec_p[b * ADIM + a] = s;
}

// ------- energies v17: v16 + per-wave A-ready counters --------------------
// R5 failure diagnosis: monotone ready_a AGGREGATED two unsynchronized
// producer waves. R1's producers were throttled by the shared done backprop
// (skew capped so sum 2(kt+1) => both done); v15 removed A backpressure, so
// wave 8 free-runs: ready_a=9 can be w8@6+w9@3, consumer reads tile 3's rows
// 64-127 stale -> timing-dependent energy corruption (absmax 0.0347).
// Fix: ready_a0/ready_a1, consumer waits BOTH >= kt+1. (ready_b's aggregate
// is provably safe: done_b gate caps each wave at i+1 increments.)
template <int FUSED>
__global__ __launch_bounds__(768)
void energies_kernel(const float* __restrict__ enc,     // [B,T,E] fp32
                     const float* __restrict__ Wenc,    // [A,E] fp32
                     const float* __restrict__ pa,      // [B,T]
                     const float* __restrict__ convw,   // [F,1,K]
                     const float* __restrict__ Wloc,    // [A,F]
                     const float* __restrict__ We,      // [A]
                     const float* __restrict__ be,      // [1]
                     const float* __restrict__ dec_p_g, // [B,A] (FUSED=0)
                     const float* __restrict__ dec,     // [B,D] (FUSED=1)
                     const float* __restrict__ Wdec,    // [A,D] (FUSED=1)
                     float* __restrict__ energ,         // [B,T]
                     float* __restrict__ pm,            // [B,4] local max
                     float* __restrict__ ps,            // [B,4] local sum
                     float* __restrict__ pctx) {        // [B,4,E] partial ctx
  __shared__ ushort A_s[128 * ASTR];       // 133,120 B persistent enc bf16
  __shared__ ushort B_s[2 * 128 * BSTR];   // 20,480 B Wenc dbuf (stride 40)
  __shared__ float cw_t[KW * 32];          // 3,968 B  transposed conv w
  __shared__ float pa_s[160];
  __shared__ float e_s[128];
  __shared__ float dps[ADIM];
  __shared__ float2 red_c[256];            // 2,048 B  phase-B reduction
  __shared__ float ms[1];
  __shared__ int ready_a0, ready_a1, ready_b[2], done_b[2], conv_done, dp_done;

  const int tid  = threadIdx.x;
  const int b    = blockIdx.y;
  const int chunk = blockIdx.x;
  const int t0b  = chunk * 128;
  const int wave = tid >> 6, lane = tid & 63;

  if (tid == 0) {
    ready_a0 = ready_a1 = 0;
    ready_b[0] = ready_b[1] = 0;
    done_b[0] = done_b[1] = 0;
    conv_done = 0;
    dp_done = 0;
  }
  if (tid >= 512 && tid < 512 + 158) {
    int gt = t0b - 15 + (tid - 512);
    pa_s[tid - 512] = (gt >= 0 && gt < TDIM) ? pa[b * TDIM + gt] : 0.f;
  }
  if (tid < 512)
    for (int id = tid; id < FDIM * KW; id += 512)
      cw_t[(id % KW) * 32 + (id / KW)] = convw[id];   // [k][f]
  __syncthreads();   // flags zeroed, pa_s/cw_t staged

  if (wave >= 8) {
    const int p = wave & 1;               // which half of the 128 rows
    if (wave < 10) {
      // ---- A producers (waves 8,9): enc -> persistent A_s
      // per-wave ready counter (the R5 bugfix)
      int* myra = (p == 0) ? &ready_a0 : &ready_a1;
      const float* gbase = enc + ((size_t)(b * TDIM + t0b)) * EDIM;
      floatx4 v[8];
      #pragma unroll
      for (int j = 0; j < 4; ++j) {
        int idx = j * 64 + lane;
        int row = p * 64 + (idx >> 2), c = idx & 3;
        const float* g = gbase + (size_t)row * EDIM + c * 8;
        v[2 * j]     = *(const floatx4*)g;
        v[2 * j + 1] = *(const floatx4*)(g + 4);
      }
      for (int kt = 0; kt < 16; ++kt) {
        #pragma unroll
        for (int j = 0; j < 4; ++j) {
          int idx = j * 64 + lane;
          int row = p * 64 + (idx >> 2), c = idx & 3;
          *(short8*)&A_s[row * ASTR + kt * 32 + c * 8] =
              pack8(v[2 * j], v[2 * j + 1]);
        }
        __threadfence_block();
        if (lane == 0) add_rel(myra);
        if (kt < 15) {
          #pragma unroll
          for (int j = 0; j < 4; ++j) {
            int idx = j * 64 + lane;
            int row = p * 64 + (idx >> 2), c = idx & 3;
            const float* g = gbase + (size_t)row * EDIM + (kt + 1) * 32 + c * 8;
            v[2 * j]     = *(const floatx4*)g;
            v[2 * j + 1] = *(const floatx4*)(g + 4);
          }
        }
      }
      if constexpr (FUSED) {
        // idle tail: dec projection, 128 threads x full D row (Wdec L2-hot)
        const int a = (wave - 8) * 64 + lane;   // 0..127
        const float* dv = dec + (size_t)b * DDIM;
        const float* wv = Wdec + (size_t)a * DDIM;
        float s = 0.f;
        #pragma unroll 8
        for (int it = 0; it < 256; ++it) {
          floatx4 d4 = *(const floatx4*)(dv + it * 4);
          floatx4 w4 = *(const floatx4*)(wv + it * 4);
          s += d4[0] * w4[0] + d4[1] * w4[1] + d4[2] * w4[2] + d4[3] * w4[3];
        }
        dps[a] = s;
        __threadfence_block();
        if (lane == 0) add_rel(&dp_done);
      }
    } else {
      // ---- B producers (waves 10,11): Wenc dbuf with done_b backpressure
      floatx4 v[8];
      #pragma unroll
      for (int j = 0; j < 4; ++j) {
        int idx = j * 64 + lane;
        int row = p * 64 + (idx >> 2), c = idx & 3;
        const float* g = Wenc + (size_t)row * EDIM + c * 8;
        v[2 * j]     = *(const floatx4*)g;
        v[2 * j + 1] = *(const floatx4*)(g + 4);
      }
      for (int kt = 0; kt < 16; ++kt) {
        const int s = kt & 1, i = kt >> 1;
        if (kt >= 2)
          while (ld_acq(&done_b[s]) < 8 * i) __builtin_amdgcn_s_sleep(10);
        ushort* slot = B_s + s * 128 * BSTR;
        #pragma unroll
        for (int j = 0; j < 4; ++j) {
          int idx = j * 64 + lane;
          int row = p * 64 + (idx >> 2), c = idx & 3;
          *(short8*)&slot[row * BSTR + c * 8] = pack8(v[2 * j], v[2 * j + 1]);
        }
        __threadfence_block();
        if (lane == 0) add_rel(&ready_b[s]);
        if (kt < 15) {
          #pragma unroll
          for (int j = 0; j < 4; ++j) {
            int idx = j * 64 + lane;
            int row = p * 64 + (idx >> 2), c = idx & 3;
            const float* g = Wenc + (size_t)row * EDIM + (kt + 1) * 32 + c * 8;
            v[2 * j]     = *(const floatx4*)g;
            v[2 * j + 1] = *(const floatx4*)(g + 4);
          }
        }
      }
    }
  } else {
    // ---------------- consumers (waves 0-7) ----------------
    const int lc = lane & 15, lq = lane >> 4;

    // location conv -> registers (write to LDS deferred to after k-loop)
    float cv[8] = {0.f, 0.f, 0.f, 0.f, 0.f, 0.f, 0.f, 0.f};
    {
      const int tl = tid >> 2, fg = tid & 3;
      #pragma unroll
      for (int k = 0; k < KW; ++k) {
        float p = pa_s[tl + k];
        floatx4 c0 = *(const floatx4*)&cw_t[k * 32 + fg * 8];
        floatx4 c1 = *(const floatx4*)&cw_t[k * 32 + fg * 8 + 4];
        #pragma unroll
        for (int n = 0; n < 4; ++n) cv[n] += p * c0[n];
        #pragma unroll
        for (int n = 0; n < 4; ++n) cv[4 + n] += p * c1[n];
      }
    }

    floatx4 acc[8];
    #pragma unroll
    for (int aT = 0; aT < 8; ++aT) acc[aT] = (floatx4){0.f, 0.f, 0.f, 0.f};

    for (int kt = 0; kt < 16; ++kt) {
      const int s = kt & 1, i = kt >> 1;
      const int need_a = kt + 1, need_b = 2 * (i + 1);
      while (ld_acq(&ready_a0) < need_a || ld_acq(&ready_a1) < need_a ||
             ld_acq(&ready_b[s]) < need_b)
        __builtin_amdgcn_s_sleep(6);
      short8 af = *(const short8*)&A_s[(wave * 16 + lc) * ASTR + kt * 32 + lq * 8];
      const ushort* Bs_ = B_s + s * 128 * BSTR;
      #pragma unroll
      for (int aT = 0; aT < 8; ++aT) {
        short8 bf = *(const short8*)&Bs_[(aT * 16 + lc) * BSTR + lq * 8];
        acc[aT] = __builtin_amdgcn_mfma_f32_16x16x32_bf16(af, bf, acc[aT], 0, 0, 0);
      }
      if (lane == 0) add_rel(&done_b[s]);
    }

    // park conv in B slot 0 (dead once all waves are past kt=14)
    while (ld_acq(&done_b[0]) < 64) __builtin_amdgcn_s_sleep(6);
    {
      const int row = wave * 16 + (lane >> 2), fg = lane & 3;
      *(short8*)&B_s[row * BSTR + fg * 8] =
          pack8((floatx4){cv[0], cv[1], cv[2], cv[3]},
                (floatx4){cv[4], cv[5], cv[6], cv[7]});
    }
    __threadfence_block();
    if (lane == 0) add_rel(&conv_done);
    while (ld_acq(&conv_done) < 8) __builtin_amdgcn_s_sleep(6);
    {
      short8 afl = *(const short8*)&B_s[(wave * 16 + lc) * BSTR + lq * 8];
      #pragma unroll
      for (int aT = 0; aT < 8; ++aT) {
        const float* g = Wloc + (size_t)(aT * 16 + lc) * FDIM + lq * 8;
        short8 bfl = pack8(*(const floatx4*)g, *(const floatx4*)(g + 4));
        acc[aT] = __builtin_amdgcn_mfma_f32_16x16x32_bf16(afl, bfl, acc[aT], 0, 0, 0);
      }
    }

    // epilogue (within-wave): e[t] = sum_a tanh(x + dp)*We + be
    const float be0 = be[0];
    float dpv[8], wev[8];
    if constexpr (FUSED) {
      while (ld_acq(&dp_done) < 2) __builtin_amdgcn_s_sleep(6);
    }
    #pragma unroll
    for (int aT = 0; aT < 8; ++aT) {
      int a = aT * 16 + lc;
      dpv[aT] = FUSED ? dps[a] : dec_p_g[b * ADIM + a];
      wev[aT] = We[a];
    }
    {
      float es[4] = {0.f, 0.f, 0.f, 0.f};
      #pragma unroll
      for (int aT = 0; aT < 8; ++aT)
        #pragma unroll
        for (int i = 0; i < 4; ++i)
          es[i] += fast_tanh(acc[aT][i] + dpv[aT]) * wev[aT];
      #pragma unroll
      for (int m = 1; m < 16; m <<= 1)
        #pragma unroll
        for (int i = 0; i < 4; ++i) es[i] += __shfl_xor(es[i], m, 64);
      if (lc == 0) {
        floatx4 ev = {es[0] + be0, es[1] + be0, es[2] + be0, es[3] + be0};
        *(floatx4*)&energ[(size_t)b * TDIM + t0b + wave * 16 + lq * 4] = ev;
        if (FUSED) *(floatx4*)&e_s[wave * 16 + lq * 4] = ev;
      }
    }
  }

  if constexpr (!FUSED) return;

  // ------- phase B: local softmax stats + partial ctx from LDS bf16 enc ----
  __syncthreads();   // join producers & consumers; e_s complete

  if (wave == 0) {
    float x0 = e_s[lane], x1 = e_s[lane + 64];
    float m = fmaxf(x0, x1);
    #pragma unroll
    for (int off = 1; off < 64; off <<= 1) m = fmaxf(m, __shfl_xor(m, off, 64));
    float sum = __expf(x0 - m) + __expf(x1 - m);
    #pragma unroll
    for (int off = 1; off < 64; off <<= 1) sum += __shfl_xor(sum, off, 64);
    if (lane == 0) {
      ms[0] = m;
      pm[b * 4 + chunk] = m;
      ps[b * 4 + chunk] = sum;
    }
  }
  __syncthreads();
  const float mI = ms[0];
  if (tid < 128) e_s[tid] = __expf(e_s[tid] - mI);   // in-place -> weights
  __syncthreads();

  // partial ctx: 512 threads, 2 cols each, 2 t-groups of 64; LDS-only reads.
  float2 cacc = make_float2(0.f, 0.f);
  const int g = tid >> 8, cp = tid & 255;
  if (tid < 512) {
    #pragma unroll 8
    for (int t = g * 64; t < g * 64 + 64; ++t) {
      float w = e_s[t];
      unsigned v = *(const unsigned*)&A_s[t * ASTR + 2 * cp];
      cacc.x += w * bf16_lo(v);
      cacc.y += w * bf16_hi(v);
    }
    if (g == 1) red_c[cp] = cacc;
  }
  __syncthreads();
  if (tid < 256) {
    float2 o = red_c[cp];
    o.x += cacc.x; o.y += cacc.y;
    *(float2*)&pctx[((size_t)(b * 4 + chunk)) * EDIM + 2 * cp] = o;
  }
}

// ---- combine: 4-way split-softmax merge. grid (B), 512 thr ---------------
__global__ __launch_bounds__(512)
void combine_kernel(const float* __restrict__ energ,   // [B,T]
                    const float* __restrict__ pm,      // [B,4]
                    const float* __restrict__ ps,      // [B,4]
                    const float* __restrict__ pctx,    // [B,4,E]
                    float* __restrict__ attn,          // [B,T]
                    float* __restrict__ ctx) {         // [B,E]
  const int b = blockIdx.x, tid = threadIdx.x;
  const float m0 = pm[b * 4 + 0], m1 = pm[b * 4 + 1];
  const float m2 = pm[b * 4 + 2], m3 = pm[b * 4 + 3];
  const float M = fmaxf(fmaxf(m0, m1), fmaxf(m2, m3));
  const float r0 = __expf(m0 - M), r1 = __expf(m1 - M);
  const float r2 = __expf(m2 - M), r3 = __expf(m3 - M);
  const float S = ps[b * 4 + 0] * r0 + ps[b * 4 + 1] * r1 +
                  ps[b * 4 + 2] * r2 + ps[b * 4 + 3] * r3;
  const float inv = 1.0f / S;
  const float e = energ[(size_t)b * TDIM + tid];
  attn[(size_t)b * TDIM + tid] = __expf(e - M) * inv;
  const float* pc = pctx + (size_t)b * 4 * EDIM + tid;
  const float c = pc[0] * r0 + pc[EDIM] * r1 + pc[2 * EDIM] * r2 +
                  pc[3 * EDIM] * r3;
  ctx[(size_t)b * EDIM + tid] = c * inv;
}

// In-place fallback (energies stored in attn slice): grid (1, B)
__global__ __launch_bounds__(256)
void softmax_context_inplace_kernel(const float* __restrict__ enc,
                                    float* __restrict__ attn,
                                    float* __restrict__ ctx) {
  __shared__ float aw[TDIM];
  __shared__ float redm[4];
  __shared__ float reds[4];
  const int b = blockIdx.y, tid = threadIdx.x;
  float* row = attn + (size_t)b * TDIM;
  float x0 = row[tid], x1 = row[tid + 256];
  float m = fmaxf(x0, x1);
  #pragma unroll
  for (int off = 32; off; off >>= 1) m = fmaxf(m, __shfl_xor(m, off, 64));
  int wid = tid >> 6, lane = tid & 63;
  if (lane == 0) redm[wid] = m;
  __syncthreads();
  m = fmaxf(fmaxf(redm[0], redm[1]), fmaxf(redm[2], redm[3]));
  float e0 = __expf(x0 - m), e1 = __expf(x1 - m);
  float s = e0 + e1;
  #pragma unroll
  for (int off = 32; off; off >>= 1) s += __shfl_xor(s, off, 64);
  if (lane == 0) reds[wid] = s;
  __syncthreads();
  s = reds[0] + reds[1] + reds[2] + reds[3];
  float inv = 1.0f / s;
  float w0 = e0 * inv, w1 = e1 * inv;
  row[tid] = w0; row[tid + 256] = w1;
  aw[tid] = w0; aw[tid + 256] = w1;
  __syncthreads();
  const float* ep = enc + ((size_t)b * TDIM) * EDIM;
  float a0 = 0.f, a1 = 0.f;
  #pragma unroll 8
  for (int t = 0; t < TDIM; ++t) {
    float w = aw[t];
    a0 += w * ep[(size_t)t * EDIM + tid];
    a1 += w * ep[(size_t)t * EDIM + tid + 256];
  }
  ctx[(size_t)b * EDIM + tid] = a0;
  ctx[(size_t)b * EDIM + tid + 256] = a1;
}

}  // namespace

extern "C" void kernel_launch(void* const* d_in, const int* in_sizes, int n_in,
                              void* d_out, int out_size, void* d_ws, size_t ws_size,
                              hipStream_t stream) {
  const float* enc   = (const float*)d_in[0];
  const float* dec   = (const float*)d_in[1];
  const float* pa    = (const float*)d_in[2];
  const float* Wenc  = (const float*)d_in[3];
  const float* Wdec  = (const float*)d_in[4];
  const float* convw = (const float*)d_in[5];
  const float* Wloc  = (const float*)d_in[6];
  const float* We    = (const float*)d_in[7];
  const float* be    = (const float*)d_in[8];

  float* ctx  = (float*)d_out;                 // [B,E]
  float* attn = (float*)d_out + BATCH * EDIM;  // [B,T]

  // fused workspace layout: energ | pm | ps | pctx
  float* energ = (float*)d_ws;                          // 256 KB
  float* pm    = energ + BATCH * TDIM;                  // 2 KB
  float* ps    = pm + BATCH * 4;                        // 2 KB
  float* pctx  = ps + BATCH * 4;                        // 1 MB

  const size_t need =
      ((size_t)BATCH * TDIM + BATCH * 8 + (size_t)BATCH * 4 * EDIM) *
      sizeof(float);

  dim3 g2(TDIM / 128, BATCH);
  if (ws_size >= need) {
    energies_kernel<1><<<g2, 768, 0, stream>>>(enc, Wenc, pa, convw, Wloc, We,
                                               be, nullptr, dec, Wdec,
                                               energ, pm, ps, pctx);
    combine_kernel<<<dim3(BATCH), 512, 0, stream>>>(energ, pm, ps, pctx,
                                                    attn, ctx);
  } else if (ws_size >= (size_t)BATCH * ADIM * sizeof(float)) {
    // fallback: minimal workspace (dec_p only), energies -> attn, inplace sm
    float* dec_p = (float*)d_ws;
    dim3 g1(BATCH, 4);
    dec_proj_kernel<<<g1, 256, 0, stream>>>(dec, Wdec, dec_p);
    energies_kernel<0><<<g2, 768, 0, stream>>>(enc, Wenc, pa, convw, Wloc, We,
                                               be, dec_p, nullptr, nullptr,
                                               attn, nullptr, nullptr, nullptr);
    dim3 g3(1, BATCH);
    softmax_context_inplace_kernel<<<g3, 256, 0, stream>>>(enc, attn, ctx);
  }
}

// Round 7
// 278.926 us; speedup vs baseline: 1.1093x; 1.1093x over previous
//
#include <hip/hip_runtime.h>
#include <hip/hip_bf16.h>
#include <math.h>

namespace {
constexpr int EDIM  = 512;
constexpr int DDIM  = 1024;
constexpr int ADIM  = 128;
constexpr int FDIM  = 32;
constexpr int KW    = 31;
constexpr int BATCH = 128;
constexpr int TDIM  = 512;

constexpr int LSTR = 40;     // LDS row stride in ushorts (80 B -> 2-way banks, free)

typedef __attribute__((ext_vector_type(8))) short short8;
typedef __attribute__((ext_vector_type(4))) float floatx4;

__device__ __forceinline__ float fast_tanh(float x) {
  x = fminf(9.0f, fmaxf(-9.0f, x));
  float e = __expf(2.0f * x);
  return (e - 1.0f) / (e + 1.0f);
}

__device__ __forceinline__ ushort2 pack_bf16(float x, float y) {
  union { __hip_bfloat162 h; ushort2 u; } cv;
  cv.h = __float22bfloat162_rn(make_float2(x, y));
  return cv.u;
}

__device__ __forceinline__ short8 pack8(floatx4 a, floatx4 b) {
  union { ushort2 u[4]; short8 v; } o;
  o.u[0] = pack_bf16(a[0], a[1]); o.u[1] = pack_bf16(a[2], a[3]);
  o.u[2] = pack_bf16(b[0], b[1]); o.u[3] = pack_bf16(b[2], b[3]);
  return o.v;
}

// dec_p[b,a] = sum_d dec[b,d] * Wdec[a,d]   grid (B, 4), 256 thr
__global__ __launch_bounds__(256)
void dec_proj_kernel(const float* __restrict__ dec,
                     const float* __restrict__ Wdec,
                     float* __restrict__ dec_p) {
  int b = blockIdx.x, az = blockIdx.y;
  int tid = threadIdx.x;
  int al = tid >> 3, seg = tid & 7;
  int a = az * 32 + al;
  const float* dv = dec + (size_t)b * DDIM;
  const float* wv = Wdec + (size_t)a * DDIM;
  float s = 0.f;
  #pragma unroll 8
  for (int it = 0; it < 32; ++it) {
    int d = it * 32 + seg * 4;
    float4 d4 = *(const float4*)(dv + d);
    float4 w4 = *(const float4*)(wv + d);
    s += d4.x * w4.x + d4.y * w4.y + d4.z * w4.z + d4.w * w4.w;
  }
  s += __shfl_xor(s, 1, 64);
  s += __shfl_xor(s, 2, 64);
  s += __shfl_xor(s, 4, 64);
  if (seg == 0) dec_p[b * ADIM + a] = s;
}

// ------- energies v18: standard 2-barrier double-buffered GEMM ------------
// R6 post-mortem: the producer-consumer + LDS-persistent designs (v13-v17)
// all lost to R1's 76 us; v17 additionally emitted ~174 MB of mystery HBM
// writes (spill/scratch at 1 blk/CU + long-lived regs across spin loops).
// v18 drops ALL spin machinery: 512 threads (8 waves) that each stage AND
// compute, one __syncthreads per K-step, T14 split (issue loads early,
// pack+ds_write after the MFMAs so HBM latency hides under compute).
// Proven pieces kept verbatim from R1: stride-40 LDS layout + fragment
// addressing, register conv (parked in dead A-buf0 after the k-loop),
// loc round, tanh/We epilogue. LDS ~45.6 KB -> 2-3 blocks/CU, no flags.
__global__ __launch_bounds__(512)
void energies_kernel(const float* __restrict__ enc,     // [B,T,E] fp32
                     const float* __restrict__ Wenc,    // [A,E] fp32
                     const float* __restrict__ pa,      // [B,T]
                     const float* __restrict__ convw,   // [F,1,K]
                     const float* __restrict__ Wloc,    // [A,F]
                     const float* __restrict__ We,      // [A]
                     const float* __restrict__ be,      // [1]
                     const float* __restrict__ dec_p,   // [B,A]
                     float* __restrict__ energ) {       // [B,T]
  __shared__ ushort A_s[2][128 * LSTR];    // 20,480 B  enc tiles (dbuf)
  __shared__ ushort B_s[2][128 * LSTR];    // 20,480 B  Wenc tiles (dbuf)
  __shared__ float cw_t[KW * 32];          // 3,968 B   conv w transposed [k][f]
  __shared__ float pa_s[160];

  const int tid  = threadIdx.x;
  const int b    = blockIdx.y;
  const int t0b  = blockIdx.x * 128;
  const int wave = tid >> 6, lane = tid & 63;
  const int lc = lane & 15, lq = lane >> 4;

  // prologue staging: pa window + transposed conv weights
  if (tid < 158) {
    int gt = t0b - 15 + tid;
    pa_s[tid] = (gt >= 0 && gt < TDIM) ? pa[b * TDIM + gt] : 0.f;
  }
  for (int id = tid; id < FDIM * KW; id += 512)
    cw_t[(id % KW) * 32 + (id / KW)] = convw[id];   // [k][f]
  __syncthreads();

  // staging geometry: thread -> (row = tid>>2, col-seg = tid&3, 8 floats)
  const int srow = tid >> 2, scs = tid & 3;
  const float* aBase =
      enc + ((size_t)(b * TDIM + t0b) + srow) * EDIM + scs * 8;
  const float* bBase = Wenc + (size_t)srow * EDIM + scs * 8;
  const int sdst = srow * LSTR + scs * 8;

  // tile 0: issue loads, compute conv under their latency, then pack+write
  floatx4 la0 = *(const floatx4*)aBase, la1 = *(const floatx4*)(aBase + 4);
  floatx4 lb0 = *(const floatx4*)bBase, lb1 = *(const floatx4*)(bBase + 4);

  float cv[8] = {0.f, 0.f, 0.f, 0.f, 0.f, 0.f, 0.f, 0.f};
  {
    const int tl = tid >> 2, fg = tid & 3;
    #pragma unroll
    for (int k = 0; k < KW; ++k) {
      float p = pa_s[tl + k];
      floatx4 c0 = *(const floatx4*)&cw_t[k * 32 + fg * 8];
      floatx4 c1 = *(const floatx4*)&cw_t[k * 32 + fg * 8 + 4];
      #pragma unroll
      for (int n = 0; n < 4; ++n) cv[n] += p * c0[n];
      #pragma unroll
      for (int n = 0; n < 4; ++n) cv[4 + n] += p * c1[n];
    }
  }

  *(short8*)&A_s[0][sdst] = pack8(la0, la1);
  *(short8*)&B_s[0][sdst] = pack8(lb0, lb1);

  floatx4 acc[8];
  #pragma unroll
  for (int aT = 0; aT < 8; ++aT) acc[aT] = (floatx4){0.f, 0.f, 0.f, 0.f};

  for (int kt = 0; kt < 16; ++kt) {
    // barrier: (a) tile kt's ds_writes visible; (b) everyone done reading
    // buf[(kt+1)&1] from step kt-1 -> safe to overwrite below.
    __syncthreads();
    if (kt < 15) {   // issue next tile's global loads EARLY (T14)
      la0 = *(const floatx4*)(aBase + (kt + 1) * 32);
      la1 = *(const floatx4*)(aBase + (kt + 1) * 32 + 4);
      lb0 = *(const floatx4*)(bBase + (kt + 1) * 32);
      lb1 = *(const floatx4*)(bBase + (kt + 1) * 32 + 4);
    }
    const ushort* As_ = A_s[kt & 1];
    const ushort* Bs_ = B_s[kt & 1];
    short8 af = *(const short8*)&As_[(wave * 16 + lc) * LSTR + lq * 8];
    #pragma unroll
    for (int aT = 0; aT < 8; ++aT) {
      short8 bf = *(const short8*)&Bs_[(aT * 16 + lc) * LSTR + lq * 8];
      acc[aT] = __builtin_amdgcn_mfma_f32_16x16x32_bf16(af, bf, acc[aT], 0, 0, 0);
    }
    if (kt < 15) {   // pack + write AFTER the MFMAs (loads had time to land)
      const int d = (kt + 1) & 1;
      *(short8*)&A_s[d][sdst] = pack8(la0, la1);
      *(short8*)&B_s[d][sdst] = pack8(lb0, lb1);
    }
  }
  __syncthreads();

  // park conv in A-buf0 (dead: last read was compute(14))
  {
    const int tl = tid >> 2, fg = tid & 3;
    *(short8*)&A_s[0][tl * LSTR + fg * 8] =
        pack8((floatx4){cv[0], cv[1], cv[2], cv[3]},
              (floatx4){cv[4], cv[5], cv[6], cv[7]});
  }
  __syncthreads();

  // loc round: A = conv (A_s[0]), B = Wloc packed from global (L2-hot)
  {
    short8 afl = *(const short8*)&A_s[0][(wave * 16 + lc) * LSTR + lq * 8];
    #pragma unroll
    for (int aT = 0; aT < 8; ++aT) {
      const float* g = Wloc + (size_t)(aT * 16 + lc) * FDIM + lq * 8;
      short8 bfl = pack8(*(const floatx4*)g, *(const floatx4*)(g + 4));
      acc[aT] = __builtin_amdgcn_mfma_f32_16x16x32_bf16(afl, bfl, acc[aT], 0, 0, 0);
    }
  }

  // epilogue (within-wave): e[t] = sum_a tanh(x + dp)*We + be
  const float be0 = be[0];
  float dpv[8], wev[8];
  #pragma unroll
  for (int aT = 0; aT < 8; ++aT) {
    int a = aT * 16 + lc;
    dpv[aT] = dec_p[b * ADIM + a];
    wev[aT] = We[a];
  }
  {
    float es[4] = {0.f, 0.f, 0.f, 0.f};
    #pragma unroll
    for (int aT = 0; aT < 8; ++aT)
      #pragma unroll
      for (int i = 0; i < 4; ++i)
        es[i] += fast_tanh(acc[aT][i] + dpv[aT]) * wev[aT];
    #pragma unroll
    for (int m = 1; m < 16; m <<= 1)
      #pragma unroll
      for (int i = 0; i < 4; ++i) es[i] += __shfl_xor(es[i], m, 64);
    if (lc == 0) {
      floatx4 ev = {es[0] + be0, es[1] + be0, es[2] + be0, es[3] + be0};
      *(floatx4*)&energ[(size_t)b * TDIM + t0b + wave * 16 + lq * 4] = ev;
    }
  }
}

// ---- fused softmax + context: grid (4 e-chunks of 128, B), 256 thr --------
// (R1-proven version: vectorized float4 context, L3-roofline-bound)
__global__ __launch_bounds__(256)
void softmax_context_kernel(const float* __restrict__ enc,
                            const float* __restrict__ energ,
                            float* __restrict__ attn,
                            float* __restrict__ ctx) {
  __shared__ float aw[TDIM];
  __shared__ float redm[4];
  __shared__ float reds[4];
  __shared__ float red2[8][128];
  const int b = blockIdx.y, ex = blockIdx.x, tid = threadIdx.x;
  const float* row = energ + (size_t)b * TDIM;
  float x0 = row[tid], x1 = row[tid + 256];
  float m = fmaxf(x0, x1);
  #pragma unroll
  for (int off = 32; off; off >>= 1) m = fmaxf(m, __shfl_xor(m, off, 64));
  int wid = tid >> 6, lane = tid & 63;
  if (lane == 0) redm[wid] = m;
  __syncthreads();
  m = fmaxf(fmaxf(redm[0], redm[1]), fmaxf(redm[2], redm[3]));
  float e0 = __expf(x0 - m), e1 = __expf(x1 - m);
  float s = e0 + e1;
  #pragma unroll
  for (int off = 32; off; off >>= 1) s += __shfl_xor(s, off, 64);
  if (lane == 0) reds[wid] = s;
  __syncthreads();
  s = reds[0] + reds[1] + reds[2] + reds[3];
  float inv = 1.0f / s;
  float w0 = e0 * inv, w1 = e1 * inv;
  aw[tid] = w0; aw[tid + 256] = w1;
  if (ex == 0) {
    attn[(size_t)b * TDIM + tid] = w0;
    attn[(size_t)b * TDIM + tid + 256] = w1;
  }
  __syncthreads();
  const int c4 = (tid & 31) * 4;
  const int h  = tid >> 5;
  const float* ep = enc + (size_t)b * TDIM * EDIM + ex * 128 + c4;
  float4 acc = make_float4(0.f, 0.f, 0.f, 0.f);
  #pragma unroll 16
  for (int t = h; t < TDIM; t += 8) {
    float w = aw[t];
    float4 v = *(const float4*)(ep + (size_t)t * EDIM);
    acc.x += w * v.x; acc.y += w * v.y; acc.z += w * v.z; acc.w += w * v.w;
  }
  *(float4*)&red2[h][c4] = acc;
  __syncthreads();
  if (tid < 128) {
    float sum = 0.f;
    #pragma unroll
    for (int g = 0; g < 8; ++g) sum += red2[g][tid];
    ctx[(size_t)b * EDIM + ex * 128 + tid] = sum;
  }
}

// In-place fallback (energies stored in attn slice): grid (1, B)
__global__ __launch_bounds__(256)
void softmax_context_inplace_kernel(const float* __restrict__ enc,
                                    float* __restrict__ attn,
                                    float* __restrict__ ctx) {
  __shared__ float aw[TDIM];
  __shared__ float redm[4];
  __shared__ float reds[4];
  const int b = blockIdx.y, tid = threadIdx.x;
  float* row = attn + (size_t)b * TDIM;
  float x0 = row[tid], x1 = row[tid + 256];
  float m = fmaxf(x0, x1);
  #pragma unroll
  for (int off = 32; off; off >>= 1) m = fmaxf(m, __shfl_xor(m, off, 64));
  int wid = tid >> 6, lane = tid & 63;
  if (lane == 0) redm[wid] = m;
  __syncthreads();
  m = fmaxf(fmaxf(redm[0], redm[1]), fmaxf(redm[2], redm[3]));
  float e0 = __expf(x0 - m), e1 = __expf(x1 - m);
  float s = e0 + e1;
  #pragma unroll
  for (int off = 32; off; off >>= 1) s += __shfl_xor(s, off, 64);
  if (lane == 0) reds[wid] = s;
  __syncthreads();
  s = reds[0] + reds[1] + reds[2] + reds[3];
  float inv = 1.0f / s;
  float w0 = e0 * inv, w1 = e1 * inv;
  row[tid] = w0; row[tid + 256] = w1;
  aw[tid] = w0; aw[tid + 256] = w1;
  __syncthreads();
  const float* ep = enc + ((size_t)b * TDIM) * EDIM;
  float a0 = 0.f, a1 = 0.f;
  #pragma unroll 8
  for (int t = 0; t < TDIM; ++t) {
    float w = aw[t];
    a0 += w * ep[(size_t)t * EDIM + tid];
    a1 += w * ep[(size_t)t * EDIM + tid + 256];
  }
  ctx[(size_t)b * EDIM + tid] = a0;
  ctx[(size_t)b * EDIM + tid + 256] = a1;
}

}  // namespace

extern "C" void kernel_launch(void* const* d_in, const int* in_sizes, int n_in,
                              void* d_out, int out_size, void* d_ws, size_t ws_size,
                              hipStream_t stream) {
  const float* enc   = (const float*)d_in[0];
  const float* dec   = (const float*)d_in[1];
  const float* pa    = (const float*)d_in[2];
  const float* Wenc  = (const float*)d_in[3];
  const float* Wdec  = (const float*)d_in[4];
  const float* convw = (const float*)d_in[5];
  const float* Wloc  = (const float*)d_in[6];
  const float* We    = (const float*)d_in[7];
  const float* be    = (const float*)d_in[8];

  float* ctx  = (float*)d_out;                 // [B,E]
  float* attn = (float*)d_out + BATCH * EDIM;  // [B,T]

  float* dec_p = (float*)d_ws;                 // 64 KB
  float* energ = dec_p + BATCH * ADIM;         // 256 KB

  const size_t need = (size_t)(BATCH * ADIM + BATCH * TDIM) * sizeof(float);

  dim3 g1(BATCH, 4);
  dec_proj_kernel<<<g1, 256, 0, stream>>>(dec, Wdec, dec_p);

  dim3 g2(TDIM / 128, BATCH);
  if (ws_size >= need) {
    energies_kernel<<<g2, 512, 0, stream>>>(enc, Wenc, pa, convw, Wloc, We, be,
                                            dec_p, energ);
    dim3 g3(4, BATCH);
    softmax_context_kernel<<<g3, 256, 0, stream>>>(enc, energ, attn, ctx);
  } else {
    energies_kernel<<<g2, 512, 0, stream>>>(enc, Wenc, pa, convw, Wloc, We, be,
                                            dec_p, attn);
    dim3 g3(1, BATCH);
    softmax_context_inplace_kernel<<<g3, 256, 0, stream>>>(enc, attn, ctx);
  }
}